// Round 1
// baseline (3263.722 us; speedup 1.0000x reference)
//
#include <hip/hip_runtime.h>
#include <stdint.h>

#define BB 32
#define TT 64
#define ID 300
#define HH 168
#define CD 168
#define SS 512
#define VV 50257
#define G4 672     // 4*H
#define IC 468     // I + C
#define KP 192     // K padded for MFMA (168 -> 192 = 6*32)
#define NP 50304   // V padded to 128 (393 tiles)

typedef float f32x4 __attribute__((ext_vector_type(4)));
typedef short bf16x8 __attribute__((ext_vector_type(8)));

__device__ __forceinline__ float bf2f(unsigned short u) {
  union { unsigned int i; float f; } v; v.i = ((unsigned int)u) << 16; return v.f;
}
__device__ __forceinline__ unsigned short f2bf(float f) {
  union { float f; unsigned int u; } v; v.f = f;
  unsigned int r = v.u + 0x7fffu + ((v.u >> 16) & 1u);
  return (unsigned short)(r >> 16);
}
__device__ __forceinline__ float rcpf(float x) { return __builtin_amdgcn_rcpf(x); }

// ---------------- transpose W_ih (672x468 -> 300x672 + 168x672) and W_hh ----
__global__ void k_transpose(const float* __restrict__ Wih, const float* __restrict__ Whh,
                            float* __restrict__ WihxT, float* __restrict__ WihcT,
                            float* __restrict__ WhhT) {
  int idx = blockIdx.x * 256 + threadIdx.x;
  const int total1 = IC * G4;
  const int total = total1 + HH * G4;
  if (idx >= total) return;
  if (idx < total1) {
    int k = idx / G4, i = idx - k * G4;
    float w = Wih[i * IC + k];
    if (k < ID) WihxT[k * G4 + i] = w;
    else        WihcT[(k - ID) * G4 + i] = w;
  } else {
    int j = idx - total1;
    int k = j / G4, i = j - k * G4;
    WhhT[k * G4 + i] = Whh[i * HH + k];
  }
}

// ---------------- seq_proj -> ET[b][h][s] = bf16(exp(2*P)) -------------------
__global__ void k_seqproj(const float* __restrict__ ctx, const float* __restrict__ Ws,
                          unsigned short* __restrict__ ET) {
  const int b = blockIdx.x;
  const int s0 = blockIdx.y * 16;
  const int tid = threadIdx.x;
  __shared__ float ctxL[16 * CD];   // 16 source rows
  __shared__ float Pl[HH * 16];     // transposed P tile
  for (int idx = tid; idx < 16 * CD; idx += 256)
    ctxL[idx] = ctx[(size_t)(b * SS + s0) * CD + idx];
  __syncthreads();
  float pv[11];
  #pragma unroll
  for (int o = 0; o < 11; ++o) {
    int idx = o * 256 + tid;
    float acc = 0.f;
    if (idx < 16 * HH) {
      int s = idx / HH, h = idx - s * HH;
      const float* cr = &ctxL[s * CD];
      #pragma unroll 4
      for (int c = 0; c < CD; ++c) acc += cr[c] * Ws[c * HH + h];
    }
    pv[o] = acc;
  }
  __syncthreads();
  #pragma unroll
  for (int o = 0; o < 11; ++o) {
    int idx = o * 256 + tid;
    if (idx < 16 * HH) {
      int s = idx / HH, h = idx - s * HH;
      Pl[h * 16 + s] = pv[o];
    }
  }
  __syncthreads();
  for (int idx = tid; idx < HH * 16; idx += 256) {
    int h = idx >> 4, s = idx & 15;
    ET[(size_t)(b * HH + h) * SS + s0 + s] = f2bf(__expf(2.f * Pl[idx]));
  }
}

// ---------------- X_proj[b][t][i] = x@WihxT + b_ih + b_hh --------------------
__global__ void k_xproj(const float* __restrict__ x, const float* __restrict__ WihxT,
                        const float* __restrict__ bih, const float* __restrict__ bhh,
                        float* __restrict__ Xp) {
  const int t0 = blockIdx.x * 8;
  const int b = blockIdx.y;
  const int tid = threadIdx.x;
  __shared__ float xL[8 * ID];
  for (int idx = tid; idx < 8 * ID; idx += 256)
    xL[idx] = x[(size_t)(b * TT + t0) * ID + idx];
  __syncthreads();
  for (int i = tid; i < G4; i += 256) {
    float bias = bih[i] + bhh[i];
    float acc[8];
    #pragma unroll
    for (int tt = 0; tt < 8; ++tt) acc[tt] = bias;
    for (int k = 0; k < ID; ++k) {
      float w = WihxT[k * G4 + i];
      #pragma unroll
      for (int tt = 0; tt < 8; ++tt) acc[tt] += xL[tt * ID + k] * w;
    }
    #pragma unroll
    for (int tt = 0; tt < 8; ++tt)
      Xp[(size_t)(b * TT + t0 + tt) * G4 + i] = acc[tt];
  }
}

// ---------------- W_dec -> bf16, padded (NP x KP) ----------------------------
__global__ void k_wdec(const float* __restrict__ Wd, unsigned short* __restrict__ Wdb) {
  size_t idx = (size_t)blockIdx.x * 256 + threadIdx.x;
  int v = (int)(idx / KP), k = (int)(idx - (size_t)v * KP);
  float val = (v < VV && k < HH) ? Wd[(size_t)v * HH + k] : 0.f;
  Wdb[idx] = f2bf(val);
}

// ---------------- recurrence: one block per batch element --------------------
__global__ __launch_bounds__(512) void k_recur(
    const float* __restrict__ ctx, const int* __restrict__ lens,
    const float* __restrict__ attWx, const float* __restrict__ attb,
    const float* __restrict__ attv, const unsigned short* __restrict__ ET,
    const float* __restrict__ Xp, const float* __restrict__ WihcT,
    const float* __restrict__ WhhT, unsigned short* __restrict__ hall) {
  const int b = blockIdx.x;
  const int tid = threadIdx.x;
  __shared__ float hL[HH], cL[HH], gE[HH], vL[HH], abL[HH];
  __shared__ float part[504];
  __shared__ float ehat[512];
  __shared__ float attn[HH];
  __shared__ float gates[G4];
  __shared__ float red[8];
  __shared__ float denr, sumv;

  if (tid < HH) {
    vL[tid] = attv[tid]; abL[tid] = attb[tid];
    hL[tid] = 0.f; cL[tid] = 0.f;
  }
  __syncthreads();
  if (tid == 0) {
    float s = 0.f;
    for (int h = 0; h < HH; ++h) s += vL[h];
    sumv = s;
  }
  const int len = lens[b];
  const unsigned short* Eb = ET + (size_t)b * HH * SS + tid;
  __syncthreads();

  for (int t = 0; t < TT; ++t) {
    // --- A: a = h @ att_Wx + att_b ; g = exp(2a)
    if (tid < 504) {
      int j = tid % HH, chj = tid / HH;
      float p = 0.f;
      int h0 = chj * 56;
      #pragma unroll 8
      for (int h = h0; h < h0 + 56; ++h) p += hL[h] * attWx[h * HH + j];
      part[chj * HH + j] = p;
    }
    __syncthreads();
    if (tid < HH) {
      float a = part[tid] + part[HH + tid] + part[2 * HH + tid] + abL[tid];
      gE[tid] = __expf(2.f * a);
    }
    __syncthreads();
    // --- B: e_s = sumv - 2*sum_h v_h / (1 + g_h * E_hs); ehat = exp(e_s)
    float eacc = 0.f;
    if (tid < len) {
      #pragma unroll 4
      for (int h = 0; h < HH; ++h) {
        float E = bf2f(Eb[(size_t)h * SS]);
        eacc += vL[h] * rcpf(fmaf(gE[h], E, 1.f));
      }
    }
    float eh = (tid < len) ? __expf(sumv - 2.f * eacc) : 0.f;
    ehat[tid] = eh;
    float r = eh;
    #pragma unroll
    for (int off = 32; off > 0; off >>= 1) r += __shfl_down(r, off);
    if ((tid & 63) == 0) red[tid >> 6] = r;
    __syncthreads();
    // --- C: weighted context (unnormalized) + 1/den
    if (tid < 504) {
      int cc = tid % HH, chc = tid / HH;
      float p = 0.f;
      for (int s = chc; s < len; s += 3)
        p += ehat[s] * ctx[(size_t)(b * SS + s) * CD + cc];
      part[chc * HH + cc] = p;
    } else if (tid == 511) {
      denr = 1.f / (red[0] + red[1] + red[2] + red[3] +
                    red[4] + red[5] + red[6] + red[7]);
    }
    __syncthreads();
    if (tid < HH)
      attn[tid] = (part[tid] + part[HH + tid] + part[2 * HH + tid]) * denr;
    __syncthreads();
    // --- D: gates = Xp + WihcT^T-dot attn + WhhT^T-dot h
    const float* Xpt = Xp + (size_t)(b * TT + t) * G4;
    for (int i = tid; i < G4; i += 512) {
      float acc = Xpt[i];
      #pragma unroll 4
      for (int c = 0; c < CD; ++c) acc += WihcT[c * G4 + i] * attn[c];
      #pragma unroll 4
      for (int h = 0; h < HH; ++h) acc += WhhT[h * G4 + i] * hL[h];
      gates[i] = acc;
    }
    __syncthreads();
    // --- E: LSTM cell update (ifgo), write h (bf16, K-padded)
    if (tid < HH) {
      float ig = gates[tid], fg = gates[HH + tid];
      float gg = gates[2 * HH + tid], og = gates[3 * HH + tid];
      float si = rcpf(1.f + __expf(-ig));
      float sf = rcpf(1.f + __expf(-fg));
      float so = rcpf(1.f + __expf(-og));
      float tg = 1.f - 2.f * rcpf(1.f + __expf(2.f * gg));
      float cn = sf * cL[tid] + si * tg;
      float tc = 1.f - 2.f * rcpf(1.f + __expf(2.f * cn));
      float hn = so * tc;
      cL[tid] = cn; hL[tid] = hn;
      hall[(size_t)(b * TT + t) * KP + tid] = f2bf(hn);
    } else if (tid < KP) {
      hall[(size_t)(b * TT + t) * KP + tid] = 0;
    }
    __syncthreads();
  }
}

// ---------------- decode GEMM: out = hall(2048xKP) @ Wdb(NPxKP)^T -----------
__global__ __launch_bounds__(256) void k_decode(const unsigned short* __restrict__ hallb,
                                                const unsigned short* __restrict__ wdb,
                                                float* __restrict__ out) {
  __shared__ __align__(16) unsigned short As[128 * 64];
  __shared__ __align__(16) unsigned short Bs[128 * 64];
  const int tid = threadIdx.x;
  const int n0 = blockIdx.x * 128, m0 = blockIdx.y * 128;
  const int lane = tid & 63, wid = tid >> 6;
  const int wm = wid >> 1, wn = wid & 1;
  const int lr = lane & 15, lk = lane >> 4;
  f32x4 acc[4][4];
  #pragma unroll
  for (int i = 0; i < 4; ++i)
    #pragma unroll
    for (int j = 0; j < 4; ++j) acc[i][j] = (f32x4)0.f;

  for (int k0 = 0; k0 < KP; k0 += 64) {
    if (k0) __syncthreads();
    #pragma unroll
    for (int i = 0; i < 4; ++i) {
      int flat = i * 256 + tid;
      int row = flat >> 3;
      int col = (flat & 7) * 8;
      uint4 va = *(const uint4*)(hallb + (size_t)(m0 + row) * KP + k0 + col);
      *(uint4*)&As[row * 64 + col] = va;
      uint4 vb = *(const uint4*)(wdb + (size_t)(n0 + row) * KP + k0 + col);
      *(uint4*)&Bs[row * 64 + col] = vb;
    }
    __syncthreads();
    #pragma unroll
    for (int kk = 0; kk < 64; kk += 32) {
      bf16x8 af[4], bfr[4];
      #pragma unroll
      for (int mi = 0; mi < 4; ++mi)
        af[mi] = *(const bf16x8*)&As[(wm * 64 + mi * 16 + lr) * 64 + kk + lk * 8];
      #pragma unroll
      for (int ni = 0; ni < 4; ++ni)
        bfr[ni] = *(const bf16x8*)&Bs[(wn * 64 + ni * 16 + lr) * 64 + kk + lk * 8];
      #pragma unroll
      for (int mi = 0; mi < 4; ++mi)
        #pragma unroll
        for (int ni = 0; ni < 4; ++ni)
          acc[mi][ni] = __builtin_amdgcn_mfma_f32_16x16x32_bf16(
              af[mi], bfr[ni], acc[mi][ni], 0, 0, 0);
    }
  }
  #pragma unroll
  for (int mi = 0; mi < 4; ++mi)
    #pragma unroll
    for (int ni = 0; ni < 4; ++ni) {
      int col = n0 + wn * 64 + ni * 16 + lr;
      if (col < VV) {
        #pragma unroll
        for (int r = 0; r < 4; ++r) {
          int row = m0 + wm * 64 + mi * 16 + lk * 4 + r;
          out[(size_t)row * VV + col] = acc[mi][ni][r];
        }
      }
    }
}

extern "C" void kernel_launch(void* const* d_in, const int* in_sizes, int n_in,
                              void* d_out, int out_size, void* d_ws, size_t ws_size,
                              hipStream_t stream) {
  (void)in_sizes; (void)n_in; (void)out_size; (void)ws_size;
  const float* x     = (const float*)d_in[0];
  const float* ctx   = (const float*)d_in[1];
  const int*   lens  = (const int*)d_in[2];
  const float* Wih   = (const float*)d_in[3];
  const float* Whh   = (const float*)d_in[4];
  const float* bih   = (const float*)d_in[5];
  const float* bhh   = (const float*)d_in[6];
  const float* attWx = (const float*)d_in[7];
  const float* attWs = (const float*)d_in[8];
  const float* attb  = (const float*)d_in[9];
  const float* attv  = (const float*)d_in[10];
  const float* Wdec  = (const float*)d_in[11];
  float* out = (float*)d_out;

  char* base = (char*)d_ws;
  size_t off = 0;
  auto alloc = [&](size_t bytes) -> void* {
    off = (off + 255) & ~(size_t)255;
    void* p = base + off;
    off += bytes;
    return p;
  };
  unsigned short* ET   = (unsigned short*)alloc((size_t)BB * HH * SS * 2);
  float*          Xp   = (float*)alloc((size_t)BB * TT * G4 * 4);
  float*          WihxT= (float*)alloc((size_t)ID * G4 * 4);
  float*          WihcT= (float*)alloc((size_t)CD * G4 * 4);
  float*          WhhT = (float*)alloc((size_t)HH * G4 * 4);
  unsigned short* hall = (unsigned short*)alloc((size_t)BB * TT * KP * 2);
  unsigned short* Wdb  = (unsigned short*)alloc((size_t)NP * KP * 2);

  k_transpose<<<dim3((IC * G4 + HH * G4 + 255) / 256), dim3(256), 0, stream>>>(
      Wih, Whh, WihxT, WihcT, WhhT);
  k_seqproj<<<dim3(BB, SS / 16), dim3(256), 0, stream>>>(ctx, attWs, ET);
  k_xproj<<<dim3(TT / 8, BB), dim3(256), 0, stream>>>(x, WihxT, bih, bhh, Xp);
  k_wdec<<<dim3((int)(((size_t)NP * KP) / 256)), dim3(256), 0, stream>>>(Wdec, Wdb);
  k_recur<<<dim3(BB), dim3(512), 0, stream>>>(ctx, lens, attWx, attb, attv, ET,
                                              Xp, WihcT, WhhT, hall);
  k_decode<<<dim3(NP / 128, (BB * TT) / 128), dim3(256), 0, stream>>>(hall, Wdb, out);
}

// Round 2
// 2267.425 us; speedup vs baseline: 1.4394x; 1.4394x over previous
//
#include <hip/hip_runtime.h>
#include <stdint.h>

#define BB 32
#define TT 64
#define ID 300
#define HH 168
#define SS 512
#define VV 50257
#define G4 672     // 4*H
#define IC 468     // I + C
#define KP 192     // K padded for decode MFMA
#define NP 50304   // V padded to 128
#define NJ 8       // blocks per batch (cluster size)
#define RPB 21     // h rows per block
#define CPB 84     // gate cols per block
#define KK 336     // gate K dim (attn 168 + h 168)
#define KPAD 348   // padded K row for LDS (odd multiple of 4 floats x ... bank spread)
#define SBLK 64    // s positions per block

typedef float f32x4 __attribute__((ext_vector_type(4)));
typedef short bf16x8 __attribute__((ext_vector_type(8)));

__device__ __forceinline__ float bf2f(unsigned short u) {
  union { unsigned int i; float f; } v; v.i = ((unsigned int)u) << 16; return v.f;
}
__device__ __forceinline__ unsigned short f2bf(float f) {
  union { float f; unsigned int u; } v; v.f = f;
  unsigned int r = v.u + 0x7fffu + ((v.u >> 16) & 1u);
  return (unsigned short)(r >> 16);
}
__device__ __forceinline__ float rcpf(float x) { return __builtin_amdgcn_rcpf(x); }

// ---------------- W_ih x-part transpose (for k_xproj) -----------------------
__global__ void k_tr(const float* __restrict__ Wih, float* __restrict__ WihxT) {
  int idx = blockIdx.x * 256 + threadIdx.x;
  if (idx < ID * G4) {
    int k = idx / G4, i = idx - k * G4;
    WihxT[idx] = Wih[(size_t)i * IC + k];
  }
}

// ---------------- seq_proj -> ETs[b][s][h] = bf16(exp(2P)); ctxb bf16 -------
__global__ void k_seqproj(const float* __restrict__ ctx, const float* __restrict__ Ws,
                          unsigned short* __restrict__ ETs, unsigned short* __restrict__ ctxb) {
  const int b = blockIdx.x;
  const int s0 = blockIdx.y * 16;
  const int tid = threadIdx.x;
  __shared__ float ctxL[16 * HH];
  for (int idx = tid; idx < 16 * HH; idx += 256) {
    float v = ctx[(size_t)(b * SS + s0) * HH + idx];
    ctxL[idx] = v;
    ctxb[(size_t)(b * SS + s0) * HH + idx] = f2bf(v);
  }
  __syncthreads();
  #pragma unroll
  for (int o = 0; o < 11; ++o) {
    int idx = o * 256 + tid;
    if (idx < 16 * HH) {
      int s = idx / HH, h = idx - s * HH;
      const float* cr = &ctxL[s * HH];
      float acc = 0.f;
      #pragma unroll 4
      for (int c = 0; c < HH; ++c) acc = fmaf(cr[c], Ws[c * HH + h], acc);
      ETs[(size_t)(b * SS + s0 + s) * HH + h] = f2bf(__expf(2.f * acc));
    }
  }
}

// ---------------- X_proj[b][t][i] = x@WihxT + b_ih + b_hh --------------------
__global__ void k_xproj(const float* __restrict__ x, const float* __restrict__ WihxT,
                        const float* __restrict__ bih, const float* __restrict__ bhh,
                        float* __restrict__ Xp) {
  const int t0 = blockIdx.x * 8;
  const int b = blockIdx.y;
  const int tid = threadIdx.x;
  __shared__ float xL[8 * ID];
  for (int idx = tid; idx < 8 * ID; idx += 256)
    xL[idx] = x[(size_t)(b * TT + t0) * ID + idx];
  __syncthreads();
  for (int i = tid; i < G4; i += 256) {
    float bias = bih[i] + bhh[i];
    float acc[8];
    #pragma unroll
    for (int tt = 0; tt < 8; ++tt) acc[tt] = bias;
    for (int k = 0; k < ID; ++k) {
      float w = WihxT[k * G4 + i];
      #pragma unroll
      for (int tt = 0; tt < 8; ++tt) acc[tt] += xL[tt * ID + k] * w;
    }
    #pragma unroll
    for (int tt = 0; tt < 8; ++tt)
      Xp[(size_t)(b * TT + t0 + tt) * G4 + i] = acc[tt];
  }
}

// ---------------- W_dec -> bf16, padded (NP x KP) ----------------------------
__global__ void k_wdec(const float* __restrict__ Wd, unsigned short* __restrict__ Wdb) {
  size_t idx = (size_t)blockIdx.x * 256 + threadIdx.x;
  int v = (int)(idx / KP), k = (int)(idx - (size_t)v * KP);
  float val = (v < VV && k < HH) ? Wd[(size_t)v * HH + k] : 0.f;
  Wdb[idx] = f2bf(val);
}

// ---------------- per-cluster-slice gate weights + WxB bf16 + counters ------
__global__ void k_prep(const float* __restrict__ Wih, const float* __restrict__ Whh,
                       const float* __restrict__ attWx, float* __restrict__ WgAll,
                       unsigned short* __restrict__ WxB, unsigned int* __restrict__ cnts) {
  int idx = blockIdx.x * 256 + threadIdx.x;
  const int TOT1 = NJ * CPB * KPAD;  // 233856
  if (idx < TOT1) {
    int j8 = idx / (CPB * KPAD);
    int r = idx - j8 * (CPB * KPAD);
    int col = r / KPAD, k = r - col * KPAD;
    int gt = col / RPB, rr = j8 * RPB + (col - gt * RPB);
    int gcol = gt * HH + rr;
    float w = 0.f;
    if (k < HH) w = Wih[(size_t)gcol * IC + ID + k];
    else if (k < KK) w = Whh[(size_t)gcol * HH + (k - HH)];
    WgAll[idx] = w;
  } else if (idx < TOT1 + HH * HH) {
    int r = idx - TOT1;
    WxB[r] = f2bf(attWx[r]);
  } else if (idx < TOT1 + HH * HH + 64) {
    cnts[idx - TOT1 - HH * HH] = 0u;
  }
}

// ---------------- cluster sync (8 blocks per batch, agent-scope) ------------
__device__ __forceinline__ void cluster_sync(unsigned int* cnt, unsigned int target, int tid) {
  __syncthreads();
  if (tid == 0) {
    __hip_atomic_fetch_add(cnt, 1u, __ATOMIC_ACQ_REL, __HIP_MEMORY_SCOPE_AGENT);
    int guard = 0;
    while (__hip_atomic_load(cnt, __ATOMIC_ACQUIRE, __HIP_MEMORY_SCOPE_AGENT) < target) {
      __builtin_amdgcn_s_sleep(1);
      if (++guard > (1 << 26)) break;  // emergency valve: fail, don't hang
    }
  }
  __syncthreads();
}

// ---------------- recurrence: 8 blocks per batch, cooperative ----------------
__global__ __launch_bounds__(512, 1) void k_recur(
    const int* __restrict__ lens, const float* __restrict__ attb,
    const float* __restrict__ attv, const unsigned short* __restrict__ WxB,
    const float* __restrict__ WgAll, const unsigned short* __restrict__ ETs,
    const unsigned short* __restrict__ ctxb, const float* __restrict__ Xp,
    float* __restrict__ Hbuf, float* __restrict__ Pbuf,
    unsigned int* __restrict__ cnts, unsigned short* __restrict__ hall) {
  const int gid = blockIdx.x;
  const int b = gid & 31;
  const int j = gid >> 5;
  const int tid = threadIdx.x;

  __shared__ float WgL[CPB * KPAD];  // 116928 B: this block's gate weights, fp32
  __shared__ float red[4032];        // shared scratch for all phases
  __shared__ float vecL[KK];         // [0:168)=attn, [168:336)=h
  __shared__ float gE[HH], vL[HH], abL[HH];
  __shared__ float esh[SBLK];
  __shared__ float gatesL[CPB];
  __shared__ float cLoc[RPB];
  __shared__ float denr_s, bsum_s, sumv_s;

  unsigned int* cntA = cnts;
  unsigned int* cntB = cnts + 32;

  // stage gate weight slice once
  {
    const f32x4* src = (const f32x4*)(WgAll + (size_t)j * CPB * KPAD);
    f32x4* dst = (f32x4*)WgL;
    for (int idx = tid; idx < CPB * KPAD / 4; idx += 512) dst[idx] = src[idx];
  }
  if (tid < HH) {
    vL[tid] = attv[tid];
    abL[tid] = attb[tid];
    vecL[tid] = 0.f;
    vecL[HH + tid] = 0.f;  // h0 = 0
  }
  if (tid < RPB) cLoc[tid] = 0.f;
  __syncthreads();
  if (tid == 0) {
    float s = 0.f;
    for (int h = 0; h < HH; ++h) s += vL[h];
    sumv_s = s;
  }
  const int len = lens[b];

  for (int t = 0; t < TT; ++t) {
    __syncthreads();
    // --- A (redundant per block): a = h@Wx + att_b ; g = exp(2a)
    if (tid < 504) {
      int hs = tid / 21, jc = tid - hs * 21;
      const unsigned short* wp = WxB + (hs * 7) * HH + jc * 8;
      float acc[8];
      #pragma unroll
      for (int r = 0; r < 8; ++r) acc[r] = 0.f;
      #pragma unroll
      for (int i = 0; i < 7; ++i) {
        float hv = vecL[HH + hs * 7 + i];
        bf16x8 w8 = *(const bf16x8*)(wp + (size_t)i * HH);
        #pragma unroll
        for (int r = 0; r < 8; ++r)
          acc[r] = fmaf(hv, bf2f((unsigned short)w8[r]), acc[r]);
      }
      #pragma unroll
      for (int r = 0; r < 8; ++r) red[tid * 8 + r] = acc[r];
    }
    __syncthreads();
    if (tid < HH) {
      int jc = tid >> 3, r = tid & 7;
      float s = 0.f;
      #pragma unroll
      for (int hs = 0; hs < 24; ++hs) s += red[(hs * 21 + jc) * 8 + r];
      gE[tid] = __expf(2.f * (s + abL[tid]));
    }
    __syncthreads();
    // --- B: e_s for this block's s-range; ehat = exp(e_s)
    {
      int sl = tid & 63, hs = tid >> 6;
      float ep = 0.f;
      if (hs < 7) {
        int sg = j * SBLK + sl;
        if (sg < len) {
          const unsigned short* erow = ETs + (size_t)(b * SS + sg) * HH + hs * 24;
          #pragma unroll
          for (int ch = 0; ch < 3; ++ch) {
            bf16x8 e8 = *(const bf16x8*)(erow + ch * 8);
            #pragma unroll
            for (int r = 0; r < 8; ++r) {
              int h = hs * 24 + ch * 8 + r;
              float E = bf2f((unsigned short)e8[r]);
              ep += vL[h] * rcpf(fmaf(gE[h], E, 1.f));
            }
          }
        }
        red[hs * 64 + sl] = ep;
      }
    }
    __syncthreads();
    if (tid < SBLK) {
      float tot = 0.f;
      #pragma unroll
      for (int hs = 0; hs < 7; ++hs) tot += red[hs * 64 + tid];
      float eh = (j * SBLK + tid < len) ? __expf(sumv_s - 2.f * tot) : 0.f;
      esh[tid] = eh;
      float r = eh;
      #pragma unroll
      for (int off = 32; off; off >>= 1) r += __shfl_down(r, off);
      if (tid == 0) bsum_s = r;
    }
    __syncthreads();
    // --- C: attn partials over this block's s-range
    if (tid < 504) {
      int c = tid % HH, sl3 = tid / HH;
      const unsigned short* cb = ctxb + (size_t)(b * SS + j * SBLK) * HH + c;
      float p = 0.f;
      for (int s = sl3; s < SBLK; s += 3)
        p = fmaf(esh[s], bf2f(cb[(size_t)s * HH]), p);
      red[tid] = p;
    }
    __syncthreads();
    if (tid < HH) {
      float v = red[tid] + red[HH + tid] + red[2 * HH + tid];
      __hip_atomic_store(&Pbuf[(size_t)(b * NJ + j) * 176 + tid], v,
                         __ATOMIC_RELAXED, __HIP_MEMORY_SCOPE_AGENT);
    } else if (tid == HH) {
      __hip_atomic_store(&Pbuf[(size_t)(b * NJ + j) * 176 + HH], bsum_s,
                         __ATOMIC_RELAXED, __HIP_MEMORY_SCOPE_AGENT);
    }
    cluster_sync(&cntA[b], (unsigned)(NJ * (t + 1)), tid);
    // --- reduce partials -> attn (normalized) in vecL[0:168)
    if (tid < 169) {
      float s = 0.f;
      #pragma unroll
      for (int jj = 0; jj < NJ; ++jj)
        s += __hip_atomic_load(&Pbuf[(size_t)(b * NJ + jj) * 176 + tid],
                               __ATOMIC_RELAXED, __HIP_MEMORY_SCOPE_AGENT);
      if (tid < HH) red[tid] = s;
      else denr_s = 1.f / s;
    }
    __syncthreads();
    if (tid < HH) vecL[tid] = red[tid] * denr_s;
    __syncthreads();
    // --- D: gates for this block's 84 columns (weights LDS-resident)
    if (tid < 504) {
      int col = tid % CPB, ks = tid / CPB;
      const float* wrow = &WgL[col * KPAD + ks * 56];
      float acc = 0.f;
      #pragma unroll
      for (int i = 0; i < 14; ++i) {
        f32x4 w4 = *(const f32x4*)(wrow + i * 4);
        int k = ks * 56 + i * 4;
        acc += w4.x * vecL[k] + w4.y * vecL[k + 1] + w4.z * vecL[k + 2] + w4.w * vecL[k + 3];
      }
      red[tid] = acc;
    }
    __syncthreads();
    if (tid < CPB) {
      int gt = tid / RPB, rr = tid - gt * RPB;
      int gcol = gt * HH + j * RPB + rr;
      float g = Xp[(size_t)(b * TT + t) * G4 + gcol];
      #pragma unroll
      for (int ks = 0; ks < 6; ++ks) g += red[ks * CPB + tid];
      gatesL[tid] = g;
    }
    __syncthreads();
    // --- E: LSTM update for this block's 21 rows
    if (tid < RPB) {
      float ig = gatesL[tid], fg = gatesL[RPB + tid];
      float gg = gatesL[2 * RPB + tid], og = gatesL[3 * RPB + tid];
      float si = rcpf(1.f + __expf(-ig));
      float sf = rcpf(1.f + __expf(-fg));
      float so = rcpf(1.f + __expf(-og));
      float tg = 1.f - 2.f * rcpf(1.f + __expf(2.f * gg));
      float cn = fmaf(sf, cLoc[tid], si * tg);
      float tc = 1.f - 2.f * rcpf(1.f + __expf(2.f * cn));
      float hn = so * tc;
      cLoc[tid] = cn;
      int rg = j * RPB + tid;
      __hip_atomic_store(&Hbuf[(size_t)((t + 1) & 1) * BB * HH + b * HH + rg], hn,
                         __ATOMIC_RELAXED, __HIP_MEMORY_SCOPE_AGENT);
      hall[(size_t)(b * TT + t) * KP + rg] = f2bf(hn);
    } else if (j == NJ - 1 && tid >= CPB && tid < CPB + 24) {
      hall[(size_t)(b * TT + t) * KP + HH + (tid - CPB)] = 0;
    }
    cluster_sync(&cntB[b], (unsigned)(NJ * (t + 1)), tid);
    if (tid < HH)
      vecL[HH + tid] = __hip_atomic_load(&Hbuf[(size_t)((t + 1) & 1) * BB * HH + b * HH + tid],
                                         __ATOMIC_RELAXED, __HIP_MEMORY_SCOPE_AGENT);
  }
}

// ---------------- decode GEMM: out = hall(2048xKP) @ Wdb(NPxKP)^T -----------
__global__ __launch_bounds__(256) void k_decode(const unsigned short* __restrict__ hallb,
                                                const unsigned short* __restrict__ wdb,
                                                float* __restrict__ out) {
  __shared__ __align__(16) unsigned short As[128 * 64];
  __shared__ __align__(16) unsigned short Bs[128 * 64];
  const int tid = threadIdx.x;
  const int n0 = blockIdx.x * 128, m0 = blockIdx.y * 128;
  const int lane = tid & 63, wid = tid >> 6;
  const int wm = wid >> 1, wn = wid & 1;
  const int lr = lane & 15, lk = lane >> 4;
  f32x4 acc[4][4];
  #pragma unroll
  for (int i = 0; i < 4; ++i)
    #pragma unroll
    for (int jj = 0; jj < 4; ++jj) acc[i][jj] = (f32x4)0.f;

  for (int k0 = 0; k0 < KP; k0 += 64) {
    if (k0) __syncthreads();
    #pragma unroll
    for (int i = 0; i < 4; ++i) {
      int flat = i * 256 + tid;
      int row = flat >> 3;
      int col = (flat & 7) * 8;
      uint4 va = *(const uint4*)(hallb + (size_t)(m0 + row) * KP + k0 + col);
      *(uint4*)&As[row * 64 + col] = va;
      uint4 vb = *(const uint4*)(wdb + (size_t)(n0 + row) * KP + k0 + col);
      *(uint4*)&Bs[row * 64 + col] = vb;
    }
    __syncthreads();
    #pragma unroll
    for (int kk = 0; kk < 64; kk += 32) {
      bf16x8 af[4], bfr[4];
      #pragma unroll
      for (int mi = 0; mi < 4; ++mi)
        af[mi] = *(const bf16x8*)&As[(wm * 64 + mi * 16 + lr) * 64 + kk + lk * 8];
      #pragma unroll
      for (int ni = 0; ni < 4; ++ni)
        bfr[ni] = *(const bf16x8*)&Bs[(wn * 64 + ni * 16 + lr) * 64 + kk + lk * 8];
      #pragma unroll
      for (int mi = 0; mi < 4; ++mi)
        #pragma unroll
        for (int ni = 0; ni < 4; ++ni)
          acc[mi][ni] = __builtin_amdgcn_mfma_f32_16x16x32_bf16(
              af[mi], bfr[ni], acc[mi][ni], 0, 0, 0);
    }
  }
  #pragma unroll
  for (int mi = 0; mi < 4; ++mi)
    #pragma unroll
    for (int ni = 0; ni < 4; ++ni) {
      int col = n0 + wn * 64 + ni * 16 + lr;
      if (col < VV) {
        #pragma unroll
        for (int r = 0; r < 4; ++r) {
          int row = m0 + wm * 64 + mi * 16 + lk * 4 + r;
          out[(size_t)row * VV + col] = acc[mi][ni][r];
        }
      }
    }
}

extern "C" void kernel_launch(void* const* d_in, const int* in_sizes, int n_in,
                              void* d_out, int out_size, void* d_ws, size_t ws_size,
                              hipStream_t stream) {
  (void)in_sizes; (void)n_in; (void)out_size; (void)ws_size;
  const float* x     = (const float*)d_in[0];
  const float* ctx   = (const float*)d_in[1];
  const int*   lens  = (const int*)d_in[2];
  const float* Wih   = (const float*)d_in[3];
  const float* Whh   = (const float*)d_in[4];
  const float* bih   = (const float*)d_in[5];
  const float* bhh   = (const float*)d_in[6];
  const float* attWx = (const float*)d_in[7];
  const float* attWs = (const float*)d_in[8];
  const float* attb  = (const float*)d_in[9];
  const float* attv  = (const float*)d_in[10];
  const float* Wdec  = (const float*)d_in[11];
  float* out = (float*)d_out;

  char* base = (char*)d_ws;
  size_t off = 0;
  auto alloc = [&](size_t bytes) -> void* {
    off = (off + 255) & ~(size_t)255;
    void* p = base + off;
    off += bytes;
    return p;
  };
  unsigned short* ETs  = (unsigned short*)alloc((size_t)BB * SS * HH * 2);
  unsigned short* ctxb = (unsigned short*)alloc((size_t)BB * SS * HH * 2);
  float*          Xp   = (float*)alloc((size_t)BB * TT * G4 * 4);
  float*          WihxT= (float*)alloc((size_t)ID * G4 * 4);
  unsigned short* hall = (unsigned short*)alloc((size_t)BB * TT * KP * 2);
  unsigned short* Wdb  = (unsigned short*)alloc((size_t)NP * KP * 2);
  float*          WgAll= (float*)alloc((size_t)NJ * CPB * KPAD * 4);
  unsigned short* WxB  = (unsigned short*)alloc((size_t)HH * HH * 2);
  float*          Hbuf = (float*)alloc((size_t)2 * BB * HH * 4);
  float*          Pbuf = (float*)alloc((size_t)BB * NJ * 176 * 4);
  unsigned int*   cnts = (unsigned int*)alloc(64 * 4);

  k_tr<<<dim3((ID * G4 + 255) / 256), dim3(256), 0, stream>>>(Wih, WihxT);
  k_seqproj<<<dim3(BB, SS / 16), dim3(256), 0, stream>>>(ctx, attWs, ETs, ctxb);
  k_xproj<<<dim3(TT / 8, BB), dim3(256), 0, stream>>>(x, WihxT, bih, bhh, Xp);
  k_wdec<<<dim3((int)(((size_t)NP * KP) / 256)), dim3(256), 0, stream>>>(Wdec, Wdb);
  k_prep<<<dim3(1024), dim3(256), 0, stream>>>(Wih, Whh, attWx, WgAll, WxB, cnts);

  {
    const int* a0 = lens; const float* a1 = attb; const float* a2 = attv;
    const unsigned short* a3 = WxB; const float* a4 = WgAll;
    const unsigned short* a5 = ETs; const unsigned short* a6 = ctxb;
    const float* a7 = Xp; float* a8 = Hbuf; float* a9 = Pbuf;
    unsigned int* a10 = cnts; unsigned short* a11 = hall;
    void* args[] = { &a0, &a1, &a2, &a3, &a4, &a5, &a6, &a7, &a8, &a9, &a10, &a11 };
    hipLaunchCooperativeKernel((void*)k_recur, dim3(BB * NJ), dim3(512), args, 0, stream);
  }

  k_decode<<<dim3(NP / 128, (BB * TT) / 128), dim3(256), 0, stream>>>(hall, Wdb, out);
}